// Round 18
// baseline (136.741 us; speedup 1.0000x reference)
//
#include <hip/hip_runtime.h>

// Shape: (B=2, C=1, D=160, H=192, W=160) fp32. win=9/dim, win_size=9 (faithful bug).
#define B_ 2
#define D_ 160
#define H_ 192
#define W_ 160
#define HW_ (H_ * W_)
#define DHW_ (D_ * HW_)
#define NV_ ((long long)B_ * D_ * H_ * W_)

// K1: block = one (b,z) slice x one 32-wide x-tile; full H staged in LDS.
#define XT 32
#define NXT (W_ / XT)        // 5
#define SCOLS 40             // staged cols: XT + 8 halo
#define SSTR 52              // LDS row stride in halves (8B-aligned rows, ~2-way banks)
#define YCH1 6               // output rows per thread (32 yc x 8 xg = 256 thr)

// K2: streaming z-window; thread = 4 cols, z-chunk of 16.
#define ZCH3 16
#define NZC3 (D_ / ZCH3)     // 10

// A2 slab layout: [bz][xt][y][c][x32] fp16; fully xy-box-summed maps.
#define SLAB ((size_t)H_ * 5 * XT)   // 30720 halves per (bz,xt)
#define A2_Z ((size_t)NXT * SLAB)    // z-stride in halves

typedef _Float16 half4 __attribute__((ext_vector_type(4)));

__global__ void k_zero(double* acc) { *acc = 0.0; }

__device__ __forceinline__ float4 h2f(const half4 h) {
    return make_float4((float)h.x, (float)h.y, (float)h.z, (float)h.w);
}
__device__ __forceinline__ void add4h(float4& d, const half4 v) {
    d.x += (float)v.x; d.y += (float)v.y; d.z += (float)v.z; d.w += (float)v.w;
}
__device__ __forceinline__ void sub4h(float4& d, const half4 v) {
    d.x -= (float)v.x; d.y -= (float)v.y; d.z -= (float)v.z; d.w -= (float)v.w;
}

// Add/sub one row's 5 products (for one 4-col group t) into ys[t][0..4].
template<int SGN>
__device__ __forceinline__ void accP(float4 ys[3][5], int t, const float4 a, const float4 b) {
    if (SGN > 0) {
        ys[t][0].x += a.x;     ys[t][0].y += a.y;     ys[t][0].z += a.z;     ys[t][0].w += a.w;
        ys[t][1].x += b.x;     ys[t][1].y += b.y;     ys[t][1].z += b.z;     ys[t][1].w += b.w;
        ys[t][2].x += a.x*a.x; ys[t][2].y += a.y*a.y; ys[t][2].z += a.z*a.z; ys[t][2].w += a.w*a.w;
        ys[t][3].x += b.x*b.x; ys[t][3].y += b.y*b.y; ys[t][3].z += b.z*b.z; ys[t][3].w += b.w*b.w;
        ys[t][4].x += a.x*b.x; ys[t][4].y += a.y*b.y; ys[t][4].z += a.z*b.z; ys[t][4].w += a.w*b.w;
    } else {
        ys[t][0].x -= a.x;     ys[t][0].y -= a.y;     ys[t][0].z -= a.z;     ys[t][0].w -= a.w;
        ys[t][1].x -= b.x;     ys[t][1].y -= b.y;     ys[t][1].z -= b.z;     ys[t][1].w -= b.w;
        ys[t][2].x -= a.x*a.x; ys[t][2].y -= a.y*a.y; ys[t][2].z -= a.z*a.z; ys[t][2].w -= a.w*a.w;
        ys[t][3].x -= b.x*b.x; ys[t][3].y -= b.y*b.y; ys[t][3].z -= b.z*b.z; ys[t][3].w -= b.w*b.w;
        ys[t][4].x -= a.x*b.x; ys[t][4].y -= a.y*b.y; ys[t][4].z -= a.z*b.z; ys[t][4].w -= a.w*b.w;
    }
}

template<int SGN>
__device__ __forceinline__ void accRow(float4 ys[3][5],
                                       const _Float16* sIrow, const _Float16* sJrow,
                                       int x4) {
#pragma unroll
    for (int t = 0; t < 3; ++t) {
        const float4 a = h2f(*(const half4*)(sIrow + x4 + t * 4));
        const float4 b = h2f(*(const half4*)(sJrow + x4 + t * 4));
        accP<SGN>(ys, t, a, b);
    }
}

// ---------------------------------------------------------------------------
// K1: stage full-H 40-col strips of I,J (fp16) once; each thread keeps 12-col
// sliding y-sums (3x5 float4) and computes the 9-tap x-window IN REGISTERS,
// writing fully xy-summed A2 to a block-contiguous slab (full-line writes).
// ---------------------------------------------------------------------------
__global__ __launch_bounds__(256) void k1_xysum(const float* __restrict__ I,
                                                const float* __restrict__ J,
                                                _Float16* __restrict__ A2) {
    __shared__ _Float16 sI[H_][SSTR];        // 19.97 KB
    __shared__ _Float16 sJ[H_][SSTR];        // 19.97 KB
    const int tid = threadIdx.x;             // 0..255
    const int xt  = blockIdx.x % NXT;
    const int bz  = blockIdx.x / NXT;        // b*D + z
    const int xs0 = xt * XT - 4;             // global x of staged col 0

    const float* Ib = I + (size_t)bz * HW_;
    const float* Jb = J + (size_t)bz * HW_;

    // ---- stage: 192 rows x 10 float4-groups = 1920 per map ----
#pragma unroll
    for (int i = 0; i < 8; ++i) {
        const int idx = i * 256 + tid;       // 0..2047
        if (idx < H_ * 10) {
            const int row = idx / 10;
            const int g   = idx - row * 10;
            const int gx  = xs0 + g * 4;     // aligned (xs0 = 32k-4)
            half4 hi, hj;
            hi.x = hi.y = hi.z = hi.w = (_Float16)0.f;
            hj.x = hj.y = hj.z = hj.w = (_Float16)0.f;
            if (gx >= 0 && gx + 3 < W_) {
                const float4 vi = *(const float4*)(Ib + (size_t)row * W_ + gx);
                const float4 vj = *(const float4*)(Jb + (size_t)row * W_ + gx);
                hi.x = (_Float16)vi.x; hi.y = (_Float16)vi.y; hi.z = (_Float16)vi.z; hi.w = (_Float16)vi.w;
                hj.x = (_Float16)vj.x; hj.y = (_Float16)vj.y; hj.z = (_Float16)vj.z; hj.w = (_Float16)vj.w;
            }
            *(half4*)&sI[row][g * 4] = hi;
            *(half4*)&sJ[row][g * 4] = hj;
        }
    }
    __syncthreads();

    // ---- compute: thread = (xg 0..7, yc 0..31); 6 output rows each ----
    const int xg = tid & 7;
    const int yc = tid >> 3;
    const int x4 = xg * 4;                   // staged col of 12-col window start
    const int y0 = yc * YCH1;

    _Float16* Ap = A2 + ((size_t)bz * NXT + xt) * SLAB + x4;

    float4 ys[3][5];
#pragma unroll
    for (int t = 0; t < 3; ++t)
#pragma unroll
        for (int c = 0; c < 5; ++c) ys[t][c] = make_float4(0, 0, 0, 0);

#pragma unroll
    for (int j = 0; j < 9; ++j) {            // prime rows [y0-5, y0+3]
        const int yr = y0 - 5 + j;           // y0+3 <= 189 < H_
        if (yr >= 0) accRow<+1>(ys, &sI[yr][0], &sJ[yr][0], x4);
    }

#pragma unroll
    for (int k = 0; k < YCH1; ++k) {
        const int yi = y0 + k + 4;           // lead
        if (yi < H_) accRow<+1>(ys, &sI[yi][0], &sJ[yi][0], x4);
        const int yo = y0 + k - 5;           // trail
        if (yo >= 0) accRow<-1>(ys, &sI[yo][0], &sJ[yo][0], x4);

        _Float16* Ay = Ap + (size_t)(y0 + k) * (5 * XT);
#pragma unroll
        for (int c = 0; c < 5; ++c) {
            // 12 values v0..v11 = ys[0][c],ys[1][c],ys[2][c]; o_j = sum v_j..v_{j+8}
            const float4 u = ys[0][c], v = ys[1][c], w = ys[2][c];
            const float o0 = u.x + u.y + u.z + u.w + v.x + v.y + v.z + v.w + w.x;
            const float o1 = o0 - u.x + w.y;
            const float o2 = o1 - u.y + w.z;
            const float o3 = o2 - u.z + w.w;
            half4 h;
            h.x = (_Float16)o0; h.y = (_Float16)o1; h.z = (_Float16)o2; h.w = (_Float16)o3;
            *(half4*)(Ay + c * XT) = h;
        }
    }
}

// ---------------------------------------------------------------------------
// K2: pure streaming z-window + cc + reduction. No LDS, no barriers: thread
// owns 4 cols, marches a z-chunk of 16 with s[c] += lead - trail, cc directly.
// Wave reads are contiguous (8 lanes x 5ch x 64B = 320B runs, 8 y-rows/wave).
// ---------------------------------------------------------------------------
__global__ __launch_bounds__(256) void k2_zcc(const _Float16* __restrict__ A2,
                                              double* __restrict__ acc) {
    const int tid = threadIdx.x;             // 0..255
    const int xl4 = (tid & 7) * 4;           // 0..28
    const int yl  = tid >> 3;                // 0..31
    int t = blockIdx.x;
    const int zc   = t % NZC3;  t /= NZC3;
    const int xt   = t % NXT;   t /= NXT;
    const int ygrp = t;                      // 0..11
    const int gy   = ygrp * 32 + yl;         // 0..383
    const int b    = gy / H_;
    const int yy   = gy - b * H_;
    const int z0   = zc * ZCH3;

    const _Float16* base = A2 + (size_t)(b * D_) * A2_Z + (size_t)xt * SLAB
                              + (size_t)yy * (5 * XT) + xl4;

    float4 s[5];
#pragma unroll
    for (int c = 0; c < 5; ++c) s[c] = make_float4(0, 0, 0, 0);

#pragma unroll
    for (int j = 0; j < 9; ++j) {            // prime slices [z0-5, z0+3]
        const int zi = z0 - 5 + j;           // z0+3 <= 147 < D_
        if (zi >= 0) {
            const _Float16* p = base + (size_t)zi * A2_Z;
#pragma unroll
            for (int c = 0; c < 5; ++c) add4h(s[c], *(const half4*)(p + c * XT));
        }
    }

    float local = 0.f;
    const float inv9 = 1.0f / 9.0f;
#pragma unroll
    for (int k = 0; k < ZCH3; ++k) {
        const int zi = z0 + k + 4;
        if (zi < D_) {
            const _Float16* p = base + (size_t)zi * A2_Z;
#pragma unroll
            for (int c = 0; c < 5; ++c) add4h(s[c], *(const half4*)(p + c * XT));
        }
        const int zo = z0 + k - 5;
        if (zo >= 0) {
            const _Float16* p = base + (size_t)zo * A2_Z;
#pragma unroll
            for (int c = 0; c < 5; ++c) sub4h(s[c], *(const half4*)(p + c * XT));
        }
        {
            const float cr = s[4].x - s[1].x * s[0].x * inv9;
            const float iv = s[2].x - s[0].x * s[0].x * inv9;
            const float jv = s[3].x - s[1].x * s[1].x * inv9;
            local += cr * cr / (iv * jv + 1e-5f);
        }
        {
            const float cr = s[4].y - s[1].y * s[0].y * inv9;
            const float iv = s[2].y - s[0].y * s[0].y * inv9;
            const float jv = s[3].y - s[1].y * s[1].y * inv9;
            local += cr * cr / (iv * jv + 1e-5f);
        }
        {
            const float cr = s[4].z - s[1].z * s[0].z * inv9;
            const float iv = s[2].z - s[0].z * s[0].z * inv9;
            const float jv = s[3].z - s[1].z * s[1].z * inv9;
            local += cr * cr / (iv * jv + 1e-5f);
        }
        {
            const float cr = s[4].w - s[1].w * s[0].w * inv9;
            const float iv = s[2].w - s[0].w * s[0].w * inv9;
            const float jv = s[3].w - s[1].w * s[1].w * inv9;
            local += cr * cr / (iv * jv + 1e-5f);
        }
    }

    __shared__ float red[256];
    red[tid] = local;
    __syncthreads();
    for (int off = 128; off > 0; off >>= 1) {
        if (tid < off) red[tid] += red[tid + off];
        __syncthreads();
    }
    if (tid == 0) atomicAdd(acc, (double)red[0]);
}

// ---------------------------------------------------------------------------
// Fallback (workspace too small): direct clipped 9x9x9 sums per voxel.
// ---------------------------------------------------------------------------
__global__ void p_direct(const float* __restrict__ I, const float* __restrict__ J,
                         double* __restrict__ acc) {
    const long long idx = (long long)blockIdx.x * blockDim.x + threadIdx.x;
    float local = 0.f;
    if (idx < NV_) {
        const int x = (int)(idx % W_);
        long long t = idx / W_;
        const int y = (int)(t % H_);
        t /= H_;
        const int z = (int)(t % D_);
        const int b = (int)(t / D_);
        const int z0 = max(z - 4, 0), z1 = min(z + 4, D_ - 1);
        const int y0 = max(y - 4, 0), y1 = min(y + 4, H_ - 1);
        const int x0 = max(x - 4, 0), x1 = min(x + 4, W_ - 1);
        float sI = 0.f, sJ = 0.f, sI2 = 0.f, sJ2 = 0.f, sIJ = 0.f;
        for (int zz = z0; zz <= z1; ++zz)
            for (int yy = y0; yy <= y1; ++yy) {
                const size_t row = ((size_t)(b * D_ + zz) * H_ + yy) * W_;
                for (int xx = x0; xx <= x1; ++xx) {
                    const float a = I[row + xx];
                    const float bb = J[row + xx];
                    sI += a; sJ += bb; sI2 += a * a; sJ2 += bb * bb; sIJ += a * bb;
                }
            }
        const float inv9 = 1.0f / 9.0f;
        const float cross = sIJ - sJ * sI * inv9;
        const float iv    = sI2 - sI * sI * inv9;
        const float jv    = sJ2 - sJ * sJ * inv9;
        local = cross * cross / (iv * jv + 1e-5f);
    }
    __shared__ float red[256];
    red[threadIdx.x] = local;
    __syncthreads();
    for (int off = 128; off > 0; off >>= 1) {
        if (threadIdx.x < off) red[threadIdx.x] += red[threadIdx.x + off];
        __syncthreads();
    }
    if (threadIdx.x == 0) atomicAdd(acc, (double)red[0]);
}

__global__ void k_final(const double* __restrict__ acc, float* __restrict__ out) {
    out[0] = (float)(-(*acc) / (double)NV_);
}

extern "C" void kernel_launch(void* const* d_in, const int* in_sizes, int n_in,
                              void* d_out, int out_size, void* d_ws, size_t ws_size,
                              hipStream_t stream) {
    const float* I = (const float*)d_in[0];  // y_true
    const float* J = (const float*)d_in[1];  // y_pred
    float* out = (float*)d_out;

    const size_t needA = (size_t)5 * B_ * DHW_ * sizeof(_Float16);  // 98.3 MB
    if (ws_size >= 1024 + needA) {
        double* acc = (double*)d_ws;
        _Float16* A2 = (_Float16*)((char*)d_ws + 1024);
        k_zero<<<1, 1, 0, stream>>>(acc);
        k1_xysum<<<B_ * D_ * NXT, 256, 0, stream>>>(I, J, A2);
        k2_zcc<<<NZC3 * NXT * (B_ * H_ / 32), 256, 0, stream>>>(A2, acc);
        k_final<<<1, 1, 0, stream>>>(acc, out);
    } else if (ws_size >= sizeof(double)) {
        double* acc = (double*)d_ws;
        k_zero<<<1, 1, 0, stream>>>(acc);
        p_direct<<<(int)((NV_ + 255) / 256), 256, 0, stream>>>(I, J, acc);
        k_final<<<1, 1, 0, stream>>>(acc, out);
    }
}